// Round 7
// baseline (422.538 us; speedup 1.0000x reference)
//
#include <hip/hip_runtime.h>
#include <math.h>

typedef unsigned short ushort_t;
typedef short s16x8 __attribute__((ext_vector_type(8)));
typedef float f32x4 __attribute__((ext_vector_type(4)));

#define MFMA16(a, b, c) __builtin_amdgcn_mfma_f32_16x16x32_bf16(a, b, c, 0, 0, 0)

#define BATCH 4
#define SEQ   1025
#define CH    768
#define HEADS 12
#define NBH   48
#define NKPAD 1088
#define NTILE 17
#define NQT   68          // 1088 / 16 query sub-blocks
#define MROWS 4100
#define SCALE2 0.18033688011112042f   // 0.125 * log2(e)

__device__ __forceinline__ ushort_t f2bf(float f) {
    unsigned u = __builtin_bit_cast(unsigned, f);
    u += 0x7FFFu + ((u >> 16) & 1u);
    return (ushort_t)(u >> 16);
}
__device__ __forceinline__ unsigned pack_bf2(float lo, float hi) {
    return (unsigned)f2bf(lo) | ((unsigned)f2bf(hi) << 16);
}
__device__ __forceinline__ float fast_exp2(float x) {
    float r; asm("v_exp_f32 %0, %1" : "=v"(r) : "v"(x)); return r;
}

// ---------------- fp32 tiled GEMM (q only): qf = x @ w_qkv[:, :768] ----------------
// Per-output accumulation stays a single k-ascending fp32 FMA chain (same numerics
// as rounds 1-6) so the data-dependent mask bits stay exactly reproducible.
__global__ __launch_bounds__(256) void gemm_f32(
    const float* __restrict__ A, const float* __restrict__ Bm,
    float* __restrict__ Cm, int M, int K, int ldb, int Nn)
{
    __shared__ float As[32][132];
    __shared__ float Bs[32][64];
    int t = threadIdx.x;
    int m0 = blockIdx.y * 128, n0 = blockIdx.x * 64;
    int tx = t & 15, ty = t >> 4;
    int laRow = t >> 2, laK = (t & 3) * 4;
    int lbK = t >> 4, lbN = (t & 15) * 4;
    float acc[8][4] = {};
    for (int k0 = 0; k0 < K; k0 += 32) {
        #pragma unroll
        for (int kh = 0; kh < 2; ++kh)
            #pragma unroll
            for (int rh = 0; rh < 2; ++rh) {
                int arow = m0 + laRow + 64 * rh;
                float4 av = make_float4(0.f, 0.f, 0.f, 0.f);
                if (arow < M) av = *(const float4*)(A + (size_t)arow * K + k0 + laK + 16 * kh);
                As[laK + 16 * kh + 0][laRow + 64 * rh] = av.x;
                As[laK + 16 * kh + 1][laRow + 64 * rh] = av.y;
                As[laK + 16 * kh + 2][laRow + 64 * rh] = av.z;
                As[laK + 16 * kh + 3][laRow + 64 * rh] = av.w;
            }
        #pragma unroll
        for (int kh = 0; kh < 2; ++kh)
            *(float4*)&Bs[lbK + 16 * kh][lbN] =
                *(const float4*)(Bm + (size_t)(k0 + lbK + 16 * kh) * ldb + n0 + lbN);
        __syncthreads();
        #pragma unroll
        for (int kk = 0; kk < 32; ++kk) {
            float4 a0 = *(const float4*)&As[kk][ty * 8];
            float4 a1 = *(const float4*)&As[kk][ty * 8 + 4];
            float4 b4 = *(const float4*)&Bs[kk][tx * 4];
            float av[8] = {a0.x, a0.y, a0.z, a0.w, a1.x, a1.y, a1.z, a1.w};
            float bv[4] = {b4.x, b4.y, b4.z, b4.w};
            #pragma unroll
            for (int i = 0; i < 8; ++i)
                #pragma unroll
                for (int j = 0; j < 4; ++j) acc[i][j] += av[i] * bv[j];
        }
        __syncthreads();
    }
    #pragma unroll
    for (int i = 0; i < 8; ++i) {
        int row = m0 + ty * 8 + i;
        if (row >= M) continue;
        *(float4*)(Cm + (size_t)row * Nn + n0 + tx * 4) =
            make_float4(acc[i][0], acc[i][1], acc[i][2], acc[i][3]);
    }
}

// ---------------- x f32 -> bf16 ----------------
__global__ __launch_bounds__(256) void convx(const float* __restrict__ x,
                                             ushort_t* __restrict__ xb, int n4)
{
    int i = blockIdx.x * 256 + threadIdx.x;
    if (i >= n4) return;
    float4 v = ((const float4*)x)[i];
    ushort_t o[4] = {f2bf(v.x), f2bf(v.y), f2bf(v.z), f2bf(v.w)};
    *(uint2*)(xb + (size_t)i * 4) = *(const uint2*)o;
}

// ---------------- transpose + convert: dst[n][k] = bf16(src[k][c0+n]) ----------------
__global__ __launch_bounds__(256) void convT(const float* __restrict__ src, int ld,
                                             int c0, ushort_t* __restrict__ dst)
{
    __shared__ float tile[32][33];
    int k0 = blockIdx.x * 32, n0 = blockIdx.y * 32;
    int t = threadIdx.x, tx = t & 31, ty = t >> 5;
    #pragma unroll
    for (int i = 0; i < 32; i += 8)
        tile[ty + i][tx] = src[(size_t)(k0 + ty + i) * ld + c0 + n0 + tx];
    __syncthreads();
    #pragma unroll
    for (int i = 0; i < 32; i += 8)
        dst[(size_t)(n0 + ty + i) * CH + k0 + tx] = f2bf(tile[tx][ty + i]);
}

// ---------- bf16 MFMA GEMM: full QKV -> qtb (token rows) + kb (row-major) + vtb (transposed) ----------
__global__ __launch_bounds__(256) void kvgemm(
    const ushort_t* __restrict__ xb, const ushort_t* __restrict__ wqkvT,
    ushort_t* __restrict__ qtb, ushort_t* __restrict__ kbuf, ushort_t* __restrict__ vtbuf)
{
    int t = threadIdx.x, w = t >> 6, l = t & 63;
    int l15 = l & 15, lhi = l >> 4;
    int m0 = blockIdx.x * 64 + 16 * w;
    int n0 = blockIdx.y * 64;
    int ar = m0 + l15; if (ar >= MROWS) ar = MROWS - 1;
    f32x4 acc[4] = {{0,0,0,0},{0,0,0,0},{0,0,0,0},{0,0,0,0}};
    for (int k = 0; k < CH; k += 32) {
        s16x8 af = *(const s16x8*)(xb + (size_t)ar * CH + k + lhi * 8);
        #pragma unroll
        for (int nt = 0; nt < 4; ++nt) {
            s16x8 bf_ = *(const s16x8*)(wqkvT + (size_t)(n0 + 16 * nt + l15) * CH + k + lhi * 8);
            acc[nt] = MFMA16(af, bf_, acc[nt]);
        }
    }
    #pragma unroll
    for (int nt = 0; nt < 4; ++nt)
        #pragma unroll
        for (int r = 0; r < 4; ++r) {
            int m = m0 + lhi * 4 + r;
            if (m >= MROWS) continue;
            int b = m / SEQ, tok = m % SEQ;
            int n = n0 + 16 * nt + l15;
            ushort_t val = f2bf(acc[nt][r]);
            if (n < CH) {
                int h = n >> 6, d = n & 63;
                qtb[((size_t)(b * HEADS + h) * NKPAD + tok) * 64 + d] = val;
            } else if (n < 2 * CH) {
                int c = n - CH; int h = c >> 6, d = c & 63;
                kbuf[((size_t)(b * HEADS + h) * NKPAD + tok) * 64 + d] = val;
            } else {
                int c = n - 2 * CH; int h = c >> 6, d = c & 63;
                vtbuf[((size_t)(b * HEADS + h) * 64 + d) * NKPAD + tok] = val;
            }
        }
}

// ---------------- zero the padded key rows/cols ----------------
__global__ __launch_bounds__(256) void zeropad(ushort_t* kbuf, ushort_t* vtbuf)
{
    int t = blockIdx.x * 256 + threadIdx.x;
    if (t < NBH * 63 * 64) {  // kb rows 1025..1087
        int bh = t / (63 * 64), rem = t % (63 * 64);
        kbuf[((size_t)bh * NKPAD + 1025 + rem / 64) * 64 + (rem & 63)] = 0;
    }
    if (t < NBH * 64 * 63) {  // vtb cols 1025..1087
        int bh = t / (64 * 63), rem = t % (64 * 63);
        vtbuf[((size_t)bh * 64 + rem / 63) * NKPAD + 1025 + rem % 63] = 0;
    }
}

// ---------------- q_sim (from fp32 qf) — unchanged numerics ----------------
__global__ __launch_bounds__(64) void qsim_kernel(
    const float* __restrict__ qf, const float* __restrict__ g, float* __restrict__ qsim)
{
    int idx = blockIdx.x;
    int b = idx >> 10, j = idx & 1023, n = j + 1;
    int lane = threadIdx.x;
    const float* qrow = qf + (size_t)(b * SEQ + n) * CH;
    float acc = 0.f;
    for (int h = 0; h < HEADS; ++h) {
        float qv = qrow[h * 64 + lane];
        float gv = g[h * 64 + lane];
        float sqg = qv * gv, sqq = qv * qv, sgg = gv * gv;
        #pragma unroll
        for (int off = 32; off; off >>= 1) {
            sqg += __shfl_xor(sqg, off);
            sqq += __shfl_xor(sqq, off);
            sgg += __shfl_xor(sgg, off);
        }
        acc += sqg / sqrtf(sqq * sgg);
    }
    if (lane == 0) qsim[idx] = acc * (1.0f / HEADS);
}

// ---------------- min/max normalize + active bitmasks + N0 counts ----------------
__global__ __launch_bounds__(1024) void mask_kernel(
    const float* __restrict__ qsim, unsigned char* __restrict__ posm,
    unsigned char* __restrict__ vgrp,
    unsigned long long* __restrict__ actbits, float* __restrict__ n0arr)
{
    __shared__ float wmin[16], wmax[16];
    __shared__ unsigned int sbm[4 * 2 * 34];
    __shared__ int scnt[8];
    int t = threadIdx.x;
    if (t < 4 * 2 * 34) sbm[t] = 0u;
    if (t < 8) scnt[t] = 0;
    float v[4];
    float lmin = 1e30f, lmax = -1e30f;
    #pragma unroll
    for (int b = 0; b < 4; ++b) {
        v[b] = qsim[b * 1024 + t];
        lmin = fminf(lmin, v[b]); lmax = fmaxf(lmax, v[b]);
    }
    #pragma unroll
    for (int off = 32; off; off >>= 1) {
        lmin = fminf(lmin, __shfl_xor(lmin, off));
        lmax = fmaxf(lmax, __shfl_xor(lmax, off));
    }
    if ((t & 63) == 0) { wmin[t >> 6] = lmin; wmax[t >> 6] = lmax; }
    __syncthreads();
    if (t == 0) {
        float gmin = wmin[0], gmax = wmax[0];
        for (int i = 1; i < 16; ++i) { gmin = fminf(gmin, wmin[i]); gmax = fmaxf(gmax, wmax[i]); }
        wmin[0] = gmin; wmax[0] = gmax;
    }
    __syncthreads();
    float gmin = wmin[0], den = wmax[0] - gmin;
    int pb[4], anyp = 0, anyn = 0;
    #pragma unroll
    for (int b = 0; b < 4; ++b) {
        float s = (v[b] - gmin) / den;
        pb[b] = s > 0.9f ? 1 : 0;
        anyp |= pb[b]; anyn |= (1 - pb[b]);
    }
    int k = t + 1;
    int wd = k >> 5;
    unsigned bit = 1u << (k & 31);
    #pragma unroll
    for (int b = 0; b < 4; ++b) {
        if (pb[b]) atomicOr(&sbm[(b * 2 + 0) * 34 + wd], bit);
        else       atomicOr(&sbm[(b * 2 + 1) * 34 + wd], bit);
        unsigned long long bp = __ballot(anyp && !pb[b]);
        unsigned long long bn = __ballot(anyn && pb[b]);
        if ((t & 63) == 0) {
            atomicAdd(&scnt[b * 2 + 0], (int)__popcll(bp));
            atomicAdd(&scnt[b * 2 + 1], (int)__popcll(bn));
        }
        posm[b * 1024 + t] = (unsigned char)pb[b];
    }
    vgrp[2 + t] = (unsigned char)anyn;
    if (t < 2) vgrp[t] = (unsigned char)t;
    if (t < 62) vgrp[1026 + t] = 0;
    __syncthreads();
    if (t < 4 * 2 * 34) {
        unsigned vv = sbm[t];
        if ((t % 34) == 0) vv |= 1u;       // CLS key active in every (b,grp)
        ((unsigned int*)actbits)[t] = vv;
    }
    if (t < 8) n0arr[t] = (float)scnt[t];
}

// ---------------- MFMA grouped flash attention: KV split across 4 waves ----------------
// Block = (bh, 16-query sub-block). Wave w processes key tiles w, w+4, ... with
// private (m, l, O^T); partials merged exactly in LDS at the end (flash merge).
// Query mask applied as scalar on S (mq in {0,1} commutes with the dot product).
// Kept-but-value-masked keys (logit exactly 0) enter the denominator analytically
// as n0 * 2^(-M) during the merge.
__global__ __launch_bounds__(256) void attn_mfma(
    const ushort_t* __restrict__ qtb, const ushort_t* __restrict__ kb,
    const ushort_t* __restrict__ vtb,
    const unsigned long long* __restrict__ actbits,
    const float* __restrict__ n0arr,
    const unsigned char* __restrict__ vgrp,
    const unsigned char* __restrict__ posm,
    ushort_t* __restrict__ xob, float* __restrict__ clsf)
{
    __shared__ __align__(16) ushort_t plds[4][16 * 64];
    __shared__ __align__(16) float comb[4][64][20];   // 16 O + m + l (+2 pad for b128 align)

    int t = threadIdx.x, w = t >> 6, l = t & 63;
    int l15 = l & 15, lhi = l >> 4;

    // XCD-aware bijective remap: 3264 = 8 XCDs x (6 bh x 68 qt)
    int lin = blockIdx.y * NQT + blockIdx.x;
    int xcd = lin & 7, slot = lin >> 3;
    int bh = xcd * 6 + slot / NQT;
    int qt = slot % NQT;
    int b = bh / HEADS, h = bh % HEADS;

    int qv = qt * 16 + l15;              // virtual query 0..1087 (lane-owned column)
    int g = vgrp[qv];
    float n0 = n0arr[b * 2 + g];
    float mq = 1.f;
    if (qv >= 2) {
        int j = qv - 2; if (j > 1023) j = 1023;   // clamp for pad lanes (discarded)
        int p = posm[b * 1024 + j];
        mq = (float)(g ? 1 - p : p);
    }
    float scl = SCALE2 * mq;
    const unsigned long long* abp = actbits + (size_t)b * 2 * NTILE;
    const unsigned long long* abg = g ? (abp + NTILE) : abp;

    int tok = (qv < 2) ? 0 : qv - 1;
    const ushort_t* qptr = qtb + ((size_t)bh * NKPAD + tok) * 64 + lhi * 8;
    s16x8 bq0 = *(const s16x8*)qptr;
    s16x8 bq1 = *(const s16x8*)(qptr + 32);

    f32x4 out[4] = {{0,0,0,0},{0,0,0,0},{0,0,0,0},{0,0,0,0}};  // O^T partial
    float mrow = -INFINITY;
    float lrow = 0.f;

    const ushort_t* kbase = kb + (size_t)bh * NKPAD * 64;
    const ushort_t* vbase = vtb + (size_t)bh * 64 * NKPAD;
    ushort_t* pw = plds[w];
    int swz = (l15 & 7) << 3;

    for (int tile = w; tile < NTILE; tile += 4) {
        // ---- S^T = K Q^T ----
        f32x4 s[4];
        #pragma unroll
        for (int tt = 0; tt < 4; ++tt) {
            const ushort_t* kp_ = kbase + (size_t)(tile * 64 + 16 * tt + l15) * 64 + lhi * 8;
            s16x8 ak0 = *(const s16x8*)kp_;
            s16x8 ak1 = *(const s16x8*)(kp_ + 32);
            f32x4 acc = {0, 0, 0, 0};
            acc = MFMA16(ak0, bq0, acc);
            acc = MFMA16(ak1, bq1, acc);
            s[tt] = acc;
        }
        // ---- active-key mask -> logits (log2 domain), query mask folded as scalar ----
        unsigned long long am = abg[tile];
        float smax = -INFINITY;
        #pragma unroll
        for (int tt = 0; tt < 4; ++tt) {
            unsigned nib = (unsigned)(am >> (16 * tt + 4 * lhi)) & 0xFu;
            #pragma unroll
            for (int r = 0; r < 4; ++r) {
                float sv = ((nib >> r) & 1u) ? s[tt][r] * scl : -INFINITY;
                s[tt][r] = sv;
                smax = fmaxf(smax, sv);
            }
        }
        smax = fmaxf(smax, __shfl_xor(smax, 16));
        smax = fmaxf(smax, __shfl_xor(smax, 32));
        float mnew = fmaxf(mrow, smax);
        float msafe = (mnew == -INFINITY) ? 0.f : mnew;   // NaN guard for empty tiles
        float alpha = fast_exp2(mrow - msafe);            // -inf -> 0 (state is 0 anyway)
        mrow = mnew;
        float ls = 0.f;
        #pragma unroll
        for (int tt = 0; tt < 4; ++tt)
            #pragma unroll
            for (int r = 0; r < 4; ++r) {
                float pv = fast_exp2(s[tt][r] - msafe);
                s[tt][r] = pv;
                ls += pv;
            }
        ls += __shfl_xor(ls, 16);
        ls += __shfl_xor(ls, 32);
        lrow = lrow * alpha + ls;
        #pragma unroll
        for (int dt = 0; dt < 4; ++dt) out[dt] *= alpha;
        // ---- P^T -> LDS (bf16, swizzled; wave-local, no barrier) ----
        #pragma unroll
        for (int tt = 0; tt < 4; ++tt) {
            unsigned lo = pack_bf2(s[tt][0], s[tt][1]);
            unsigned hi = pack_bf2(s[tt][2], s[tt][3]);
            int kk = 16 * tt + 4 * lhi;
            *(uint2*)&pw[(l15 * 64 + kk) ^ swz] = make_uint2(lo, hi);
        }
        // ---- PV: O^T += V^T . P^T ----
        s16x8 pb0 = *(const s16x8*)&pw[(l15 * 64 + lhi * 8) ^ swz];
        s16x8 pb1 = *(const s16x8*)&pw[(l15 * 64 + 32 + lhi * 8) ^ swz];
        #pragma unroll
        for (int dt = 0; dt < 4; ++dt) {
            const ushort_t* vp = vbase + (size_t)(16 * dt + l15) * NKPAD + tile * 64 + lhi * 8;
            s16x8 av0 = *(const s16x8*)vp;
            s16x8 av1 = *(const s16x8*)(vp + 32);
            out[dt] = MFMA16(av0, pb0, out[dt]);
            out[dt] = MFMA16(av1, pb1, out[dt]);
        }
    }

    // ---- write partials and merge across waves ----
    #pragma unroll
    for (int dt = 0; dt < 4; ++dt) *(f32x4*)&comb[w][l][4 * dt] = out[dt];
    comb[w][l][16] = mrow;
    comb[w][l][17] = lrow;
    __syncthreads();

    if (w == 0) {
        float m0_ = comb[0][l][16], m1_ = comb[1][l][16];
        float m2_ = comb[2][l][16], m3_ = comb[3][l][16];
        float M = fmaxf(fmaxf(m0_, m1_), fmaxf(m2_, m3_));
        if (n0 > 0.f) M = fmaxf(M, 0.f);      // M finite: CLS key active in wave 0
        float L = n0 * fast_exp2(0.f - M);
        f32x4 o[4] = {{0,0,0,0},{0,0,0,0},{0,0,0,0},{0,0,0,0}};
        #pragma unroll
        for (int w2 = 0; w2 < 4; ++w2) {
            float a = fast_exp2(comb[w2][l][16] - M);   // -inf -> 0
            L += comb[w2][l][17] * a;
            #pragma unroll
            for (int dt = 0; dt < 4; ++dt)
                o[dt] += *(const f32x4*)&comb[w2][l][4 * dt] * a;
        }
        float invl = 1.0f / L;
        if (qv <= 1025) {
            if (qv >= 2) {
                int n = qv - 1;
                ushort_t* dst = xob + (size_t)(b * SEQ + n) * CH + h * 64 + 4 * lhi;
                #pragma unroll
                for (int dt = 0; dt < 4; ++dt) {
                    unsigned lo = pack_bf2(o[dt][0] * invl, o[dt][1] * invl);
                    unsigned hi = pack_bf2(o[dt][2] * invl, o[dt][3] * invl);
                    *(uint2*)(dst + 16 * dt) = make_uint2(lo, hi);
                }
            } else {
                float* dst = clsf + (size_t)(qv * BATCH + b) * CH + h * 64 + 4 * lhi;
                #pragma unroll
                for (int dt = 0; dt < 4; ++dt)
                    #pragma unroll
                    for (int r = 0; r < 4; ++r)
                        dst[16 * dt + r] = o[dt][r] * invl;
            }
        }
    }
}

// ---------------- CLS combine into xob row 0 ----------------
__global__ __launch_bounds__(768) void cls_combine(
    const float* __restrict__ clsf, ushort_t* __restrict__ xob)
{
    int b = blockIdx.x, c = threadIdx.x;
    float v = 0.5f * (clsf[(size_t)b * CH + c] + clsf[(size_t)(BATCH + b) * CH + c]);
    xob[(size_t)b * SEQ * CH + c] = f2bf(v);
}

// ---------------- bf16 MFMA projection GEMM: out = xob @ wpT^T + bias (f32 out) --------
__global__ __launch_bounds__(256) void projgemm(
    const ushort_t* __restrict__ xob, const ushort_t* __restrict__ wpT,
    const float* __restrict__ bias, float* __restrict__ outp)
{
    int t = threadIdx.x, w = t >> 6, l = t & 63;
    int l15 = l & 15, lhi = l >> 4;
    int m0 = blockIdx.x * 64 + 16 * w;
    int n0 = blockIdx.y * 64;
    int ar = m0 + l15; if (ar >= MROWS) ar = MROWS - 1;
    f32x4 acc[4] = {{0,0,0,0},{0,0,0,0},{0,0,0,0},{0,0,0,0}};
    for (int k = 0; k < CH; k += 32) {
        s16x8 af = *(const s16x8*)(xob + (size_t)ar * CH + k + lhi * 8);
        #pragma unroll
        for (int nt = 0; nt < 4; ++nt) {
            s16x8 bf_ = *(const s16x8*)(wpT + (size_t)(n0 + 16 * nt + l15) * CH + k + lhi * 8);
            acc[nt] = MFMA16(af, bf_, acc[nt]);
        }
    }
    #pragma unroll
    for (int nt = 0; nt < 4; ++nt)
        #pragma unroll
        for (int r = 0; r < 4; ++r) {
            int m = m0 + lhi * 4 + r;
            if (m >= MROWS) continue;
            int n = n0 + 16 * nt + l15;
            outp[(size_t)m * CH + n] = acc[nt][r] + bias[n];
        }
}

extern "C" void kernel_launch(void* const* d_in, const int* in_sizes, int n_in,
                              void* d_out, int out_size, void* d_ws, size_t ws_size,
                              hipStream_t stream) {
    const float* x      = (const float*)d_in[0];
    const float* g_info = (const float*)d_in[1];
    const float* w_qkv  = (const float*)d_in[2];
    const float* w_proj = (const float*)d_in[3];
    const float* b_proj = (const float*)d_in[4];
    float* out = (float*)d_out;
    char* ws = (char*)d_ws;

    size_t off = 0;
    auto alloc = [&](size_t bytes) { size_t o = off; off += (bytes + 255) & ~(size_t)255; return o; };
    float*    qf    = (float*)(ws + alloc((size_t)MROWS * CH * 4));
    ushort_t* xb    = (ushort_t*)(ws + alloc((size_t)MROWS * CH * 2));
    ushort_t* wkvT  = (ushort_t*)(ws + alloc((size_t)3 * CH * CH * 2));
    ushort_t* wpT   = (ushort_t*)(ws + alloc((size_t)CH * CH * 2));
    ushort_t* qtb   = (ushort_t*)(ws + alloc((size_t)NBH * NKPAD * 64 * 2));
    ushort_t* kbuf  = (ushort_t*)(ws + alloc((size_t)NBH * NKPAD * 64 * 2));
    ushort_t* vtbuf = (ushort_t*)(ws + alloc((size_t)NBH * NKPAD * 64 * 2));
    ushort_t* xob   = (ushort_t*)(ws + alloc((size_t)MROWS * CH * 2));
    float*    clsf  = (float*)(ws + alloc((size_t)2 * BATCH * CH * 4));
    float*    qsim  = (float*)(ws + alloc((size_t)BATCH * 1024 * 4));
    unsigned char* posm = (unsigned char*)(ws + alloc((size_t)BATCH * 1024));
    unsigned long long* actbits = (unsigned long long*)(ws + alloc((size_t)BATCH * 2 * NTILE * 8));
    float* n0arr = (float*)(ws + alloc((size_t)8 * 4));
    unsigned char* vgrp = (unsigned char*)(ws + alloc((size_t)NKPAD));

    // independent prep
    convx<<<(MROWS * CH / 4 + 255) / 256, 256, 0, stream>>>(x, xb, MROWS * CH / 4);
    convT<<<dim3(CH / 32, 3 * CH / 32), 256, 0, stream>>>(w_qkv, 3 * CH, 0, wkvT);
    convT<<<dim3(CH / 32, CH / 32), 256, 0, stream>>>(w_proj, CH, 0, wpT);
    zeropad<<<(NBH * 64 * 63 + 255) / 256, 256, 0, stream>>>(kbuf, vtbuf);

    // fp32 q GEMM (mask-exact path)
    gemm_f32<<<dim3(CH / 64, (MROWS + 127) / 128), 256, 0, stream>>>(
        x, w_qkv, qf, MROWS, CH, 3 * CH, CH);
    // bf16 full-QKV GEMM with layout-transforming stores
    kvgemm<<<dim3((MROWS + 63) / 64, 3 * CH / 64), 256, 0, stream>>>(xb, wkvT, qtb, kbuf, vtbuf);

    // masks
    qsim_kernel<<<BATCH * 1024, 64, 0, stream>>>(qf, g_info, qsim);
    mask_kernel<<<1, 1024, 0, stream>>>(qsim, posm, vgrp, actbits, n0arr);

    // attention (4-way KV split per block)
    attn_mfma<<<dim3(NQT, NBH), 256, 0, stream>>>(
        qtb, kbuf, vtbuf, actbits, n0arr, vgrp, posm, xob, clsf);
    cls_combine<<<BATCH, CH, 0, stream>>>(clsf, xob);

    // projection
    projgemm<<<dim3((MROWS + 63) / 64, CH / 64), 256, 0, stream>>>(xob, wpT, b_proj, out);

    // tail output: g_info[1:]
    hipMemcpyAsync(out + (size_t)MROWS * CH, g_info + 2 * CH, (size_t)2 * CH * sizeof(float),
                   hipMemcpyDeviceToDevice, stream);
}

// Round 8
// 386.971 us; speedup vs baseline: 1.0919x; 1.0919x over previous
//
#include <hip/hip_runtime.h>
#include <math.h>

typedef unsigned short ushort_t;
typedef short s16x8 __attribute__((ext_vector_type(8)));
typedef float f32x4 __attribute__((ext_vector_type(4)));

#define MFMA16(a, b, c) __builtin_amdgcn_mfma_f32_16x16x32_bf16(a, b, c, 0, 0, 0)

#define BATCH 4
#define SEQ   1025
#define CH    768
#define HEADS 12
#define NBH   48
#define NKPAD 1088
#define NTILE 17
#define NQT   68          // 1088 / 16 query sub-blocks
#define MROWS 4100
#define SCALE2 0.18033688011112042f   // 0.125 * log2(e)

__device__ __forceinline__ ushort_t f2bf(float f) {
    unsigned u = __builtin_bit_cast(unsigned, f);
    u += 0x7FFFu + ((u >> 16) & 1u);
    return (ushort_t)(u >> 16);
}
__device__ __forceinline__ unsigned pack_bf2(float lo, float hi) {
    return (unsigned)f2bf(lo) | ((unsigned)f2bf(hi) << 16);
}
__device__ __forceinline__ float fast_exp2(float x) {
    float r; asm("v_exp_f32 %0, %1" : "=v"(r) : "v"(x)); return r;
}

// ---------------- fp32 tiled GEMM (q only): qf = x @ w_qkv[:, :768] ----------------
// Per-output accumulation stays a single k-ascending fp32 FMA chain (same numerics
// as rounds 1-7) so the data-dependent mask bits stay exactly reproducible.
__global__ __launch_bounds__(256) void gemm_f32(
    const float* __restrict__ A, const float* __restrict__ Bm,
    float* __restrict__ Cm, int M, int K, int ldb, int Nn)
{
    __shared__ float As[32][132];
    __shared__ float Bs[32][64];
    int t = threadIdx.x;
    int m0 = blockIdx.y * 128, n0 = blockIdx.x * 64;
    int tx = t & 15, ty = t >> 4;
    int laRow = t >> 2, laK = (t & 3) * 4;
    int lbK = t >> 4, lbN = (t & 15) * 4;
    float acc[8][4] = {};
    for (int k0 = 0; k0 < K; k0 += 32) {
        #pragma unroll
        for (int kh = 0; kh < 2; ++kh)
            #pragma unroll
            for (int rh = 0; rh < 2; ++rh) {
                int arow = m0 + laRow + 64 * rh;
                float4 av = make_float4(0.f, 0.f, 0.f, 0.f);
                if (arow < M) av = *(const float4*)(A + (size_t)arow * K + k0 + laK + 16 * kh);
                As[laK + 16 * kh + 0][laRow + 64 * rh] = av.x;
                As[laK + 16 * kh + 1][laRow + 64 * rh] = av.y;
                As[laK + 16 * kh + 2][laRow + 64 * rh] = av.z;
                As[laK + 16 * kh + 3][laRow + 64 * rh] = av.w;
            }
        #pragma unroll
        for (int kh = 0; kh < 2; ++kh)
            *(float4*)&Bs[lbK + 16 * kh][lbN] =
                *(const float4*)(Bm + (size_t)(k0 + lbK + 16 * kh) * ldb + n0 + lbN);
        __syncthreads();
        #pragma unroll
        for (int kk = 0; kk < 32; ++kk) {
            float4 a0 = *(const float4*)&As[kk][ty * 8];
            float4 a1 = *(const float4*)&As[kk][ty * 8 + 4];
            float4 b4 = *(const float4*)&Bs[kk][tx * 4];
            float av[8] = {a0.x, a0.y, a0.z, a0.w, a1.x, a1.y, a1.z, a1.w};
            float bv[4] = {b4.x, b4.y, b4.z, b4.w};
            #pragma unroll
            for (int i = 0; i < 8; ++i)
                #pragma unroll
                for (int j = 0; j < 4; ++j) acc[i][j] += av[i] * bv[j];
        }
        __syncthreads();
    }
    #pragma unroll
    for (int i = 0; i < 8; ++i) {
        int row = m0 + ty * 8 + i;
        if (row >= M) continue;
        *(float4*)(Cm + (size_t)row * Nn + n0 + tx * 4) =
            make_float4(acc[i][0], acc[i][1], acc[i][2], acc[i][3]);
    }
}

// ---------------- x f32 -> bf16 ----------------
__global__ __launch_bounds__(256) void convx(const float* __restrict__ x,
                                             ushort_t* __restrict__ xb, int n4)
{
    int i = blockIdx.x * 256 + threadIdx.x;
    if (i >= n4) return;
    float4 v = ((const float4*)x)[i];
    ushort_t o[4] = {f2bf(v.x), f2bf(v.y), f2bf(v.z), f2bf(v.w)};
    *(uint2*)(xb + (size_t)i * 4) = *(const uint2*)o;
}

// ---------------- transpose + convert: dst[n][k] = bf16(src[k][c0+n]) ----------------
__global__ __launch_bounds__(256) void convT(const float* __restrict__ src, int ld,
                                             int c0, ushort_t* __restrict__ dst)
{
    __shared__ float tile[32][33];
    int k0 = blockIdx.x * 32, n0 = blockIdx.y * 32;
    int t = threadIdx.x, tx = t & 31, ty = t >> 5;
    #pragma unroll
    for (int i = 0; i < 32; i += 8)
        tile[ty + i][tx] = src[(size_t)(k0 + ty + i) * ld + c0 + n0 + tx];
    __syncthreads();
    #pragma unroll
    for (int i = 0; i < 32; i += 8)
        dst[(size_t)(n0 + ty + i) * CH + k0 + tx] = f2bf(tile[tx][ty + i]);
}

// ---------------- qtb = bf16(qf) re-laid-out to (bh, tok, d) ----------------
__global__ __launch_bounds__(256) void qconv(const float* __restrict__ qf,
                                             ushort_t* __restrict__ qtb)
{
    int i = blockIdx.x * 256 + threadIdx.x;     // over MROWS * CH / 8
    if (i >= MROWS * CH / 8) return;
    int row = i / (CH / 8);
    int rem = i % (CH / 8);
    int b = row / SEQ, tok = row % SEQ;
    int h = rem >> 3, d8 = (rem & 7) * 8;
    const float* src = qf + (size_t)row * CH + h * 64 + d8;
    ushort_t o[8];
    #pragma unroll
    for (int j = 0; j < 8; ++j) o[j] = f2bf(src[j]);
    *(uint4*)(qtb + ((size_t)(b * HEADS + h) * NKPAD + tok) * 64 + d8) =
        *(const uint4*)o;
}

// ---------- bf16 MFMA GEMM: K/V only, XCD-bijective M-slab remap ----------
// 1560 blocks = 8 XCDs x 195; logical = (lin&7)*195 + (lin>>3) gives each XCD
// ~8 M-tiles x all 24 N-tiles -> per-XCD working set = B (2.4 MB) + A-slab
// (0.8 MB) < 4 MB L2, so panel re-reads become L2 hits.
__global__ __launch_bounds__(256) void kvgemm(
    const ushort_t* __restrict__ xb, const ushort_t* __restrict__ wkvT,
    ushort_t* __restrict__ kbuf, ushort_t* __restrict__ vtbuf)
{
    int t = threadIdx.x, w = t >> 6, l = t & 63;
    int l15 = l & 15, lhi = l >> 4;
    int lin = blockIdx.x;
    int logical = (lin & 7) * 195 + (lin >> 3);
    int mt = logical / 24, nt_ = logical % 24;
    int m0 = mt * 64 + 16 * w;
    int n0 = nt_ * 64;
    int ar = m0 + l15; if (ar >= MROWS) ar = MROWS - 1;
    f32x4 acc[4] = {{0,0,0,0},{0,0,0,0},{0,0,0,0},{0,0,0,0}};
    for (int k = 0; k < CH; k += 32) {
        s16x8 af = *(const s16x8*)(xb + (size_t)ar * CH + k + lhi * 8);
        #pragma unroll
        for (int nt = 0; nt < 4; ++nt) {
            s16x8 bf_ = *(const s16x8*)(wkvT + (size_t)(n0 + 16 * nt + l15) * CH + k + lhi * 8);
            acc[nt] = MFMA16(af, bf_, acc[nt]);
        }
    }
    #pragma unroll
    for (int nt = 0; nt < 4; ++nt)
        #pragma unroll
        for (int r = 0; r < 4; ++r) {
            int m = m0 + lhi * 4 + r;
            if (m >= MROWS) continue;
            int b = m / SEQ, tok = m % SEQ;
            int n = n0 + 16 * nt + l15;
            ushort_t val = f2bf(acc[nt][r]);
            if (n < CH) {
                int h = n >> 6, d = n & 63;
                kbuf[((size_t)(b * HEADS + h) * NKPAD + tok) * 64 + d] = val;
            } else {
                int c = n - CH; int h = c >> 6, d = c & 63;
                vtbuf[((size_t)(b * HEADS + h) * 64 + d) * NKPAD + tok] = val;
            }
        }
}

// ---------------- zero the padded rows/cols (k, v, q) ----------------
__global__ __launch_bounds__(256) void zeropad(ushort_t* kbuf, ushort_t* vtbuf, ushort_t* qtb)
{
    int t = blockIdx.x * 256 + threadIdx.x;
    if (t < NBH * 63 * 64) {  // kbuf + qtb rows 1025..1087
        int bh = t / (63 * 64), rem = t % (63 * 64);
        kbuf[((size_t)bh * NKPAD + 1025 + rem / 64) * 64 + (rem & 63)] = 0;
        qtb [((size_t)bh * NKPAD + 1025 + rem / 64) * 64 + (rem & 63)] = 0;
    }
    if (t < NBH * 64 * 63) {  // vtb cols 1025..1087
        int bh = t / (64 * 63), rem = t % (64 * 63);
        vtbuf[((size_t)bh * 64 + rem / 63) * NKPAD + 1025 + rem % 63] = 0;
    }
}

// ---------------- q_sim (from fp32 qf) — unchanged numerics ----------------
__global__ __launch_bounds__(64) void qsim_kernel(
    const float* __restrict__ qf, const float* __restrict__ g, float* __restrict__ qsim)
{
    int idx = blockIdx.x;
    int b = idx >> 10, j = idx & 1023, n = j + 1;
    int lane = threadIdx.x;
    const float* qrow = qf + (size_t)(b * SEQ + n) * CH;
    float acc = 0.f;
    for (int h = 0; h < HEADS; ++h) {
        float qv = qrow[h * 64 + lane];
        float gv = g[h * 64 + lane];
        float sqg = qv * gv, sqq = qv * qv, sgg = gv * gv;
        #pragma unroll
        for (int off = 32; off; off >>= 1) {
            sqg += __shfl_xor(sqg, off);
            sqq += __shfl_xor(sqq, off);
            sgg += __shfl_xor(sgg, off);
        }
        acc += sqg / sqrtf(sqq * sgg);
    }
    if (lane == 0) qsim[idx] = acc * (1.0f / HEADS);
}

// ---------------- min/max normalize + active bitmasks + N0 counts ----------------
__global__ __launch_bounds__(1024) void mask_kernel(
    const float* __restrict__ qsim, unsigned char* __restrict__ posm,
    unsigned char* __restrict__ vgrp,
    unsigned long long* __restrict__ actbits, float* __restrict__ n0arr)
{
    __shared__ float wmin[16], wmax[16];
    __shared__ unsigned int sbm[4 * 2 * 34];
    __shared__ int scnt[8];
    int t = threadIdx.x;
    if (t < 4 * 2 * 34) sbm[t] = 0u;
    if (t < 8) scnt[t] = 0;
    float v[4];
    float lmin = 1e30f, lmax = -1e30f;
    #pragma unroll
    for (int b = 0; b < 4; ++b) {
        v[b] = qsim[b * 1024 + t];
        lmin = fminf(lmin, v[b]); lmax = fmaxf(lmax, v[b]);
    }
    #pragma unroll
    for (int off = 32; off; off >>= 1) {
        lmin = fminf(lmin, __shfl_xor(lmin, off));
        lmax = fmaxf(lmax, __shfl_xor(lmax, off));
    }
    if ((t & 63) == 0) { wmin[t >> 6] = lmin; wmax[t >> 6] = lmax; }
    __syncthreads();
    if (t == 0) {
        float gmin = wmin[0], gmax = wmax[0];
        for (int i = 1; i < 16; ++i) { gmin = fminf(gmin, wmin[i]); gmax = fmaxf(gmax, wmax[i]); }
        wmin[0] = gmin; wmax[0] = gmax;
    }
    __syncthreads();
    float gmin = wmin[0], den = wmax[0] - gmin;
    int pb[4], anyp = 0, anyn = 0;
    #pragma unroll
    for (int b = 0; b < 4; ++b) {
        float s = (v[b] - gmin) / den;
        pb[b] = s > 0.9f ? 1 : 0;
        anyp |= pb[b]; anyn |= (1 - pb[b]);
    }
    int k = t + 1;
    int wd = k >> 5;
    unsigned bit = 1u << (k & 31);
    #pragma unroll
    for (int b = 0; b < 4; ++b) {
        if (pb[b]) atomicOr(&sbm[(b * 2 + 0) * 34 + wd], bit);
        else       atomicOr(&sbm[(b * 2 + 1) * 34 + wd], bit);
        unsigned long long bp = __ballot(anyp && !pb[b]);
        unsigned long long bn = __ballot(anyn && pb[b]);
        if ((t & 63) == 0) {
            atomicAdd(&scnt[b * 2 + 0], (int)__popcll(bp));
            atomicAdd(&scnt[b * 2 + 1], (int)__popcll(bn));
        }
        posm[b * 1024 + t] = (unsigned char)pb[b];
    }
    vgrp[2 + t] = (unsigned char)anyn;
    if (t < 2) vgrp[t] = (unsigned char)t;
    if (t < 62) vgrp[1026 + t] = 0;
    __syncthreads();
    if (t < 4 * 2 * 34) {
        unsigned vv = sbm[t];
        if ((t % 34) == 0) vv |= 1u;       // CLS key active in every (b,grp)
        ((unsigned int*)actbits)[t] = vv;
    }
    if (t < 8) n0arr[t] = (float)scnt[t];
}

// ---------------- MFMA grouped flash attention: KV split across 4 waves ----------------
__global__ __launch_bounds__(256) void attn_mfma(
    const ushort_t* __restrict__ qtb, const ushort_t* __restrict__ kb,
    const ushort_t* __restrict__ vtb,
    const unsigned long long* __restrict__ actbits,
    const float* __restrict__ n0arr,
    const unsigned char* __restrict__ vgrp,
    const unsigned char* __restrict__ posm,
    ushort_t* __restrict__ xob, float* __restrict__ clsf)
{
    __shared__ __align__(16) ushort_t plds[4][16 * 64];
    __shared__ __align__(16) float comb[4][64][20];   // 16 O + m + l (+2 pad)

    int t = threadIdx.x, w = t >> 6, l = t & 63;
    int l15 = l & 15, lhi = l >> 4;

    // XCD-aware bijective remap: 3264 = 8 XCDs x (6 bh x 68 qt)
    int lin = blockIdx.y * NQT + blockIdx.x;
    int xcd = lin & 7, slot = lin >> 3;
    int bh = xcd * 6 + slot / NQT;
    int qt = slot % NQT;
    int b = bh / HEADS, h = bh % HEADS;

    int qv = qt * 16 + l15;              // virtual query 0..1087 (lane-owned column)
    int g = vgrp[qv];
    float n0 = n0arr[b * 2 + g];
    float mq = 1.f;
    if (qv >= 2) {
        int j = qv - 2; if (j > 1023) j = 1023;   // clamp for pad lanes (discarded)
        int p = posm[b * 1024 + j];
        mq = (float)(g ? 1 - p : p);
    }
    float scl = SCALE2 * mq;
    const unsigned long long* abp = actbits + (size_t)b * 2 * NTILE;
    const unsigned long long* abg = g ? (abp + NTILE) : abp;

    int tok = (qv < 2) ? 0 : qv - 1;
    const ushort_t* qptr = qtb + ((size_t)bh * NKPAD + tok) * 64 + lhi * 8;
    s16x8 bq0 = *(const s16x8*)qptr;
    s16x8 bq1 = *(const s16x8*)(qptr + 32);

    f32x4 out[4] = {{0,0,0,0},{0,0,0,0},{0,0,0,0},{0,0,0,0}};  // O^T partial
    float mrow = -INFINITY;
    float lrow = 0.f;

    const ushort_t* kbase = kb + (size_t)bh * NKPAD * 64;
    const ushort_t* vbase = vtb + (size_t)bh * 64 * NKPAD;
    ushort_t* pw = plds[w];
    int swz = (l15 & 7) << 3;

    for (int tile = w; tile < NTILE; tile += 4) {
        // ---- S^T = K Q^T ----
        f32x4 s[4];
        #pragma unroll
        for (int tt = 0; tt < 4; ++tt) {
            const ushort_t* kp_ = kbase + (size_t)(tile * 64 + 16 * tt + l15) * 64 + lhi * 8;
            s16x8 ak0 = *(const s16x8*)kp_;
            s16x8 ak1 = *(const s16x8*)(kp_ + 32);
            f32x4 acc = {0, 0, 0, 0};
            acc = MFMA16(ak0, bq0, acc);
            acc = MFMA16(ak1, bq1, acc);
            s[tt] = acc;
        }
        // ---- active-key mask -> logits (log2 domain), query mask folded as scalar ----
        unsigned long long am = abg[tile];
        float smax = -INFINITY;
        #pragma unroll
        for (int tt = 0; tt < 4; ++tt) {
            unsigned nib = (unsigned)(am >> (16 * tt + 4 * lhi)) & 0xFu;
            #pragma unroll
            for (int r = 0; r < 4; ++r) {
                float sv = ((nib >> r) & 1u) ? s[tt][r] * scl : -INFINITY;
                s[tt][r] = sv;
                smax = fmaxf(smax, sv);
            }
        }
        smax = fmaxf(smax, __shfl_xor(smax, 16));
        smax = fmaxf(smax, __shfl_xor(smax, 32));
        float mnew = fmaxf(mrow, smax);
        float msafe = (mnew == -INFINITY) ? 0.f : mnew;   // NaN guard for empty tiles
        float alpha = fast_exp2(mrow - msafe);            // -inf -> 0 (state is 0 anyway)
        mrow = mnew;
        float ls = 0.f;
        #pragma unroll
        for (int tt = 0; tt < 4; ++tt)
            #pragma unroll
            for (int r = 0; r < 4; ++r) {
                float pv = fast_exp2(s[tt][r] - msafe);
                s[tt][r] = pv;
                ls += pv;
            }
        ls += __shfl_xor(ls, 16);
        ls += __shfl_xor(ls, 32);
        lrow = lrow * alpha + ls;
        #pragma unroll
        for (int dt = 0; dt < 4; ++dt) out[dt] *= alpha;
        // ---- P^T -> LDS (bf16, swizzled; wave-local, no barrier) ----
        #pragma unroll
        for (int tt = 0; tt < 4; ++tt) {
            unsigned lo = pack_bf2(s[tt][0], s[tt][1]);
            unsigned hi = pack_bf2(s[tt][2], s[tt][3]);
            int kk = 16 * tt + 4 * lhi;
            *(uint2*)&pw[(l15 * 64 + kk) ^ swz] = make_uint2(lo, hi);
        }
        // ---- PV: O^T += V^T . P^T ----
        s16x8 pb0 = *(const s16x8*)&pw[(l15 * 64 + lhi * 8) ^ swz];
        s16x8 pb1 = *(const s16x8*)&pw[(l15 * 64 + 32 + lhi * 8) ^ swz];
        #pragma unroll
        for (int dt = 0; dt < 4; ++dt) {
            const ushort_t* vp = vbase + (size_t)(16 * dt + l15) * NKPAD + tile * 64 + lhi * 8;
            s16x8 av0 = *(const s16x8*)vp;
            s16x8 av1 = *(const s16x8*)(vp + 32);
            out[dt] = MFMA16(av0, pb0, out[dt]);
            out[dt] = MFMA16(av1, pb1, out[dt]);
        }
    }

    // ---- write partials and merge across waves ----
    #pragma unroll
    for (int dt = 0; dt < 4; ++dt) *(f32x4*)&comb[w][l][4 * dt] = out[dt];
    comb[w][l][16] = mrow;
    comb[w][l][17] = lrow;
    __syncthreads();

    if (w == 0) {
        float m0_ = comb[0][l][16], m1_ = comb[1][l][16];
        float m2_ = comb[2][l][16], m3_ = comb[3][l][16];
        float M = fmaxf(fmaxf(m0_, m1_), fmaxf(m2_, m3_));
        if (n0 > 0.f) M = fmaxf(M, 0.f);      // M finite: CLS key active in wave 0
        float L = n0 * fast_exp2(0.f - M);
        f32x4 o[4] = {{0,0,0,0},{0,0,0,0},{0,0,0,0},{0,0,0,0}};
        #pragma unroll
        for (int w2 = 0; w2 < 4; ++w2) {
            float a = fast_exp2(comb[w2][l][16] - M);   // -inf -> 0
            L += comb[w2][l][17] * a;
            #pragma unroll
            for (int dt = 0; dt < 4; ++dt)
                o[dt] += *(const f32x4*)&comb[w2][l][4 * dt] * a;
        }
        float invl = 1.0f / L;
        if (qv <= 1025) {
            if (qv >= 2) {
                int n = qv - 1;
                ushort_t* dst = xob + (size_t)(b * SEQ + n) * CH + h * 64 + 4 * lhi;
                #pragma unroll
                for (int dt = 0; dt < 4; ++dt) {
                    unsigned lo = pack_bf2(o[dt][0] * invl, o[dt][1] * invl);
                    unsigned hi = pack_bf2(o[dt][2] * invl, o[dt][3] * invl);
                    *(uint2*)(dst + 16 * dt) = make_uint2(lo, hi);
                }
            } else {
                float* dst = clsf + (size_t)(qv * BATCH + b) * CH + h * 64 + 4 * lhi;
                #pragma unroll
                for (int dt = 0; dt < 4; ++dt)
                    #pragma unroll
                    for (int r = 0; r < 4; ++r)
                        dst[16 * dt + r] = o[dt][r] * invl;
            }
        }
    }
}

// ---------------- CLS combine into xob row 0 ----------------
__global__ __launch_bounds__(768) void cls_combine(
    const float* __restrict__ clsf, ushort_t* __restrict__ xob)
{
    int b = blockIdx.x, c = threadIdx.x;
    float v = 0.5f * (clsf[(size_t)b * CH + c] + clsf[(size_t)(BATCH + b) * CH + c]);
    xob[(size_t)b * SEQ * CH + c] = f2bf(v);
}

// ---------------- bf16 MFMA projection GEMM: out = xob @ wpT^T + bias (f32 out) --------
__global__ __launch_bounds__(256) void projgemm(
    const ushort_t* __restrict__ xob, const ushort_t* __restrict__ wpT,
    const float* __restrict__ bias, float* __restrict__ outp)
{
    int t = threadIdx.x, w = t >> 6, l = t & 63;
    int l15 = l & 15, lhi = l >> 4;
    int m0 = blockIdx.x * 64 + 16 * w;
    int n0 = blockIdx.y * 64;
    int ar = m0 + l15; if (ar >= MROWS) ar = MROWS - 1;
    f32x4 acc[4] = {{0,0,0,0},{0,0,0,0},{0,0,0,0},{0,0,0,0}};
    for (int k = 0; k < CH; k += 32) {
        s16x8 af = *(const s16x8*)(xob + (size_t)ar * CH + k + lhi * 8);
        #pragma unroll
        for (int nt = 0; nt < 4; ++nt) {
            s16x8 bf_ = *(const s16x8*)(wpT + (size_t)(n0 + 16 * nt + l15) * CH + k + lhi * 8);
            acc[nt] = MFMA16(af, bf_, acc[nt]);
        }
    }
    #pragma unroll
    for (int nt = 0; nt < 4; ++nt)
        #pragma unroll
        for (int r = 0; r < 4; ++r) {
            int m = m0 + lhi * 4 + r;
            if (m >= MROWS) continue;
            int n = n0 + 16 * nt + l15;
            outp[(size_t)m * CH + n] = acc[nt][r] + bias[n];
        }
}

extern "C" void kernel_launch(void* const* d_in, const int* in_sizes, int n_in,
                              void* d_out, int out_size, void* d_ws, size_t ws_size,
                              hipStream_t stream) {
    const float* x      = (const float*)d_in[0];
    const float* g_info = (const float*)d_in[1];
    const float* w_qkv  = (const float*)d_in[2];
    const float* w_proj = (const float*)d_in[3];
    const float* b_proj = (const float*)d_in[4];
    float* out = (float*)d_out;
    char* ws = (char*)d_ws;

    size_t off = 0;
    auto alloc = [&](size_t bytes) { size_t o = off; off += (bytes + 255) & ~(size_t)255; return o; };
    float*    qf    = (float*)(ws + alloc((size_t)MROWS * CH * 4));
    ushort_t* xb    = (ushort_t*)(ws + alloc((size_t)MROWS * CH * 2));
    ushort_t* wkvT  = (ushort_t*)(ws + alloc((size_t)2 * CH * CH * 2));
    ushort_t* wpT   = (ushort_t*)(ws + alloc((size_t)CH * CH * 2));
    ushort_t* qtb   = (ushort_t*)(ws + alloc((size_t)NBH * NKPAD * 64 * 2));
    ushort_t* kbuf  = (ushort_t*)(ws + alloc((size_t)NBH * NKPAD * 64 * 2));
    ushort_t* vtbuf = (ushort_t*)(ws + alloc((size_t)NBH * NKPAD * 64 * 2));
    ushort_t* xob   = (ushort_t*)(ws + alloc((size_t)MROWS * CH * 2));
    float*    clsf  = (float*)(ws + alloc((size_t)2 * BATCH * CH * 4));
    float*    qsim  = (float*)(ws + alloc((size_t)BATCH * 1024 * 4));
    unsigned char* posm = (unsigned char*)(ws + alloc((size_t)BATCH * 1024));
    unsigned long long* actbits = (unsigned long long*)(ws + alloc((size_t)BATCH * 2 * NTILE * 8));
    float* n0arr = (float*)(ws + alloc((size_t)8 * 4));
    unsigned char* vgrp = (unsigned char*)(ws + alloc((size_t)NKPAD));

    // independent prep
    convx<<<(MROWS * CH / 4 + 255) / 256, 256, 0, stream>>>(x, xb, MROWS * CH / 4);
    convT<<<dim3(CH / 32, 2 * CH / 32), 256, 0, stream>>>(w_qkv, 3 * CH, CH, wkvT);
    convT<<<dim3(CH / 32, CH / 32), 256, 0, stream>>>(w_proj, CH, 0, wpT);
    zeropad<<<(NBH * 64 * 63 + 255) / 256, 256, 0, stream>>>(kbuf, vtbuf, qtb);

    // fp32 q GEMM (mask-exact path)
    gemm_f32<<<dim3(CH / 64, (MROWS + 127) / 128), 256, 0, stream>>>(
        x, w_qkv, qf, MROWS, CH, 3 * CH, CH);
    // bf16 K/V GEMM (XCD-bijective M-slab remap)
    kvgemm<<<65 * 24, 256, 0, stream>>>(xb, wkvT, kbuf, vtbuf);

    // masks + q cast
    qsim_kernel<<<BATCH * 1024, 64, 0, stream>>>(qf, g_info, qsim);
    mask_kernel<<<1, 1024, 0, stream>>>(qsim, posm, vgrp, actbits, n0arr);
    qconv<<<(MROWS * CH / 8 + 255) / 256, 256, 0, stream>>>(qf, qtb);

    // attention (4-way KV split per block)
    attn_mfma<<<dim3(NQT, NBH), 256, 0, stream>>>(
        qtb, kbuf, vtbuf, actbits, n0arr, vgrp, posm, xob, clsf);
    cls_combine<<<BATCH, CH, 0, stream>>>(clsf, xob);

    // projection
    projgemm<<<dim3((MROWS + 63) / 64, CH / 64), 256, 0, stream>>>(xob, wpT, b_proj, out);

    // tail output: g_info[1:]
    hipMemcpyAsync(out + (size_t)MROWS * CH, g_info + 2 * CH, (size_t)2 * CH * sizeof(float),
                   hipMemcpyDeviceToDevice, stream);
}